// Round 5
// baseline (3060.317 us; speedup 1.0000x reference)
//
#include <hip/hip_runtime.h>

// STGNN K-hop propagation, CSR-by-destination.
//   norm[e] = deginv[row[e]]*deginv[col[e]]
//   b[n,:]  = sum_in norm*ef   -- computed by EDGE-NATURAL SCATTER (streams ef
//             at full HBM BW; old CSR-gather read 307MB in random 384B rows,
//             mostly HBM misses, latency-bound)
//   hop1: x1 = S*x + b; out = h0*x + h1*x1   (pure x-gather, like other hops)
//   hops 2..K: xk = S*x_{k-1} + b; out += hk*xk
// Thread mapping in hot kernels: global id g -> node = g/12, pair-chunk = g%12,
// each thread owns TWO float4s (32B) of the node's 96-dim row.

#define CH 24   // float4 chunks per 96-float row
#define CH2 12  // float4-PAIR chunks per row (32B per thread)

// Clang ext-vector for __builtin_nontemporal_load (HIP float4 is a class type,
// which the builtin rejects).
typedef float v4f __attribute__((ext_vector_type(4)));

__global__ void deg_kernel(const int* __restrict__ col, int* __restrict__ deg, int E) {
    int e = blockIdx.x * blockDim.x + threadIdx.x;
    if (e < E) atomicAdd(&deg[col[e]], 1);
}

__global__ void deginv_kernel(const int* __restrict__ deg, float* __restrict__ deginv, int n) {
    int i = blockIdx.x * blockDim.x + threadIdx.x;
    if (i < n) {
        int d = deg[i];
        deginv[i] = (d > 0) ? rsqrtf((float)d) : 0.0f;
    }
}

// b[col[e],:] += norm[e] * ef[e,:]  -- 12 threads per edge, ef read is a pure
// sequential stream (nontemporal: single-use 307MB must not thrash L3).
// Scatter targets the 19.2MB b buffer via HW f32 atomics; contention ~deg=16.
__global__ __launch_bounds__(256) void scatter_b_kernel(const int* __restrict__ row,
                                                        const int* __restrict__ col,
                                                        const float* __restrict__ deginv,
                                                        const float4* __restrict__ ef4,
                                                        float* __restrict__ bvec,
                                                        int E) {
    int g = blockIdx.x * 256 + threadIdx.x;
    int e = g / CH2;
    if (e >= E) return;
    int c = (g - e * CH2) * 2;      // float4 chunk index (0,2,...,22)
    int r = row[e], cc = col[e];
    float nrm = deginv[r] * deginv[cc];
    const v4f* fp = (const v4f*)(ef4 + (size_t)e * CH + c);
    v4f f0 = __builtin_nontemporal_load(fp);
    v4f f1 = __builtin_nontemporal_load(fp + 1);
    float* bp = bvec + (size_t)cc * (CH * 4) + c * 4;
    unsafeAtomicAdd(bp + 0, nrm * f0.x);
    unsafeAtomicAdd(bp + 1, nrm * f0.y);
    unsafeAtomicAdd(bp + 2, nrm * f0.z);
    unsafeAtomicAdd(bp + 3, nrm * f0.w);
    unsafeAtomicAdd(bp + 4, nrm * f1.x);
    unsafeAtomicAdd(bp + 5, nrm * f1.y);
    unsafeAtomicAdd(bp + 6, nrm * f1.z);
    unsafeAtomicAdd(bp + 7, nrm * f1.w);
}

// ---- hierarchical exclusive scan: 1024 elems/block ----
__global__ __launch_bounds__(256) void scan1_kernel(const int* __restrict__ deg,
                                                    int* __restrict__ starts,
                                                    int* __restrict__ bsums, int n) {
    int t = threadIdx.x;
    int i = blockIdx.x * 1024 + t * 4;
    int4 v = make_int4(0, 0, 0, 0);
    if (i + 3 < n) v = *(const int4*)(deg + i);
    else {
        if (i + 0 < n) v.x = deg[i + 0];
        if (i + 1 < n) v.y = deg[i + 1];
        if (i + 2 < n) v.z = deg[i + 2];
        if (i + 3 < n) v.w = deg[i + 3];
    }
    int s0 = v.x, s1 = s0 + v.y, s2 = s1 + v.z, s3 = s2 + v.w;
    int tot = s3;
    int lane = t & 63;
    int incl = tot;
    for (int off = 1; off < 64; off <<= 1) {
        int u = __shfl_up(incl, off, 64);
        if (lane >= off) incl += u;
    }
    __shared__ int wsum[4];
    __shared__ int woff[4];
    int wid = t >> 6;
    if (lane == 63) wsum[wid] = incl;
    __syncthreads();
    if (t == 0) { int a = 0; for (int w = 0; w < 4; ++w) { woff[w] = a; a += wsum[w]; } }
    __syncthreads();
    int excl = incl - tot + woff[wid];
    if (i + 0 < n) starts[i + 0] = excl;
    if (i + 1 < n) starts[i + 1] = excl + s0;
    if (i + 2 < n) starts[i + 2] = excl + s1;
    if (i + 3 < n) starts[i + 3] = excl + s2;
    if (t == 255) bsums[blockIdx.x] = woff[3] + wsum[3];
}

__global__ __launch_bounds__(64) void scan2_kernel(int* __restrict__ bsums, int nb,
                                                   int* __restrict__ starts, int n, int total) {
    int lane = threadIdx.x;
    int v = (lane < nb) ? bsums[lane] : 0;
    int incl = v;
    for (int off = 1; off < 64; off <<= 1) {
        int u = __shfl_up(incl, off, 64);
        if (lane >= off) incl += u;
    }
    if (lane < nb) bsums[lane] = incl - v;
    if (lane == 0) starts[n] = total;
}

__global__ __launch_bounds__(256) void scan3_kernel(int* __restrict__ starts,
                                                    int* __restrict__ cursor,
                                                    const int* __restrict__ bsums, int n) {
    int t = threadIdx.x;
    int i = blockIdx.x * 1024 + t * 4;
    int off = bsums[blockIdx.x];
    for (int k = 0; k < 4; ++k) {
        int ii = i + k;
        if (ii < n) {
            int s = starts[ii] + off;
            starts[ii] = s;
            cursor[ii] = s;
        }
    }
}

// Fill CSR slots with (row, norm) metadata (eids no longer needed -- ef is
// consumed by the edge-natural scatter, not in CSR order).
__global__ void fill_kernel(const int* __restrict__ col, const int* __restrict__ row,
                            const float* __restrict__ deginv, int* __restrict__ cursor,
                            float2* __restrict__ edat, int E) {
    int e = blockIdx.x * blockDim.x + threadIdx.x;
    if (e < E) {
        int c = col[e], r = row[e];
        int pos = atomicAdd(&cursor[c], 1);
        float2 o;
        o.x = __int_as_float(r);
        o.y = deginv[r] * deginv[c];
        edat[pos] = o;
    }
}

// hop1: x1 = S*x + b; out = h0*x + h1*x1; xnext = x1.
__global__ __launch_bounds__(256) void hop1_kernel(const int* __restrict__ starts,
                                                   const float2* __restrict__ edat,
                                                   const float4* __restrict__ x4,
                                                   const float4* __restrict__ bvec4,
                                                   float4* __restrict__ xnext4,
                                                   float4* __restrict__ out4,
                                                   const float* __restrict__ hopwise,
                                                   int NC2) {
    int g = blockIdx.x * 256 + threadIdx.x;
    if (g >= NC2) return;
    int node = g / CH2;
    int c = (g - node * CH2) * 2;
    int s = starts[node], e_end = starts[node + 1];
    float4 ax0 = make_float4(0.f, 0.f, 0.f, 0.f), ax1 = ax0;
    int j = s;
    for (; j + 4 <= e_end; j += 4) {
        float2 a0 = edat[j], a1 = edat[j + 1], a2 = edat[j + 2], a3 = edat[j + 3];
        int r0 = __float_as_int(a0.x), r1 = __float_as_int(a1.x);
        int r2 = __float_as_int(a2.x), r3 = __float_as_int(a3.x);
        const float4* p0 = x4 + (size_t)r0 * CH + c;
        const float4* p1 = x4 + (size_t)r1 * CH + c;
        const float4* p2 = x4 + (size_t)r2 * CH + c;
        const float4* p3 = x4 + (size_t)r3 * CH + c;
        float4 v00 = p0[0], v01 = p0[1];
        float4 v10 = p1[0], v11 = p1[1];
        float4 v20 = p2[0], v21 = p2[1];
        float4 v30 = p3[0], v31 = p3[1];
        ax0.x += a0.y * v00.x + a1.y * v10.x + a2.y * v20.x + a3.y * v30.x;
        ax0.y += a0.y * v00.y + a1.y * v10.y + a2.y * v20.y + a3.y * v30.y;
        ax0.z += a0.y * v00.z + a1.y * v10.z + a2.y * v20.z + a3.y * v30.z;
        ax0.w += a0.y * v00.w + a1.y * v10.w + a2.y * v20.w + a3.y * v30.w;
        ax1.x += a0.y * v01.x + a1.y * v11.x + a2.y * v21.x + a3.y * v31.x;
        ax1.y += a0.y * v01.y + a1.y * v11.y + a2.y * v21.y + a3.y * v31.y;
        ax1.z += a0.y * v01.z + a1.y * v11.z + a2.y * v21.z + a3.y * v31.z;
        ax1.w += a0.y * v01.w + a1.y * v11.w + a2.y * v21.w + a3.y * v31.w;
    }
    for (; j < e_end; ++j) {
        float2 a = edat[j];
        int r = __float_as_int(a.x);
        const float4* p = x4 + (size_t)r * CH + c;
        float4 v0 = p[0], v1 = p[1];
        ax0.x += a.y * v0.x; ax0.y += a.y * v0.y; ax0.z += a.y * v0.z; ax0.w += a.y * v0.w;
        ax1.x += a.y * v1.x; ax1.y += a.y * v1.y; ax1.z += a.y * v1.z; ax1.w += a.y * v1.w;
    }
    float h0 = hopwise[0], h1 = hopwise[1];
    size_t o = (size_t)node * CH + c;
    float4 b0 = bvec4[o], b1 = bvec4[o + 1];
    float4 x10, x11;
    x10.x = ax0.x + b0.x; x10.y = ax0.y + b0.y; x10.z = ax0.z + b0.z; x10.w = ax0.w + b0.w;
    x11.x = ax1.x + b1.x; x11.y = ax1.y + b1.y; x11.z = ax1.z + b1.z; x11.w = ax1.w + b1.w;
    xnext4[o] = x10; xnext4[o + 1] = x11;
    float4 xs0 = x4[o], xs1 = x4[o + 1];
    float4 ov0, ov1;
    ov0.x = h0 * xs0.x + h1 * x10.x; ov0.y = h0 * xs0.y + h1 * x10.y;
    ov0.z = h0 * xs0.z + h1 * x10.z; ov0.w = h0 * xs0.w + h1 * x10.w;
    ov1.x = h0 * xs1.x + h1 * x11.x; ov1.y = h0 * xs1.y + h1 * x11.y;
    ov1.z = h0 * xs1.z + h1 * x11.z; ov1.w = h0 * xs1.w + h1 * x11.w;
    out4[o] = ov0; out4[o + 1] = ov1;
}

// hops 2..K: xk = S*x_{k-1} + b; out += hk*xk.  writeNext=0 on the last hop
// (xnext is dead there; saves a 19.2MB store stream).
__global__ __launch_bounds__(256) void hop_kernel(const int* __restrict__ starts,
                                                  const float2* __restrict__ edat,
                                                  const float4* __restrict__ xcur4,
                                                  const float4* __restrict__ bvec4,
                                                  float4* __restrict__ xnext4,
                                                  float4* __restrict__ out4,
                                                  const float* __restrict__ hopwise,
                                                  int hop, int writeNext, int NC2) {
    int g = blockIdx.x * 256 + threadIdx.x;
    if (g >= NC2) return;
    int node = g / CH2;
    int c = (g - node * CH2) * 2;
    int s = starts[node], e_end = starts[node + 1];
    float4 ax0 = make_float4(0.f, 0.f, 0.f, 0.f), ax1 = ax0;
    int j = s;
    for (; j + 4 <= e_end; j += 4) {
        float2 a0 = edat[j], a1 = edat[j + 1], a2 = edat[j + 2], a3 = edat[j + 3];
        int r0 = __float_as_int(a0.x), r1 = __float_as_int(a1.x);
        int r2 = __float_as_int(a2.x), r3 = __float_as_int(a3.x);
        const float4* p0 = xcur4 + (size_t)r0 * CH + c;
        const float4* p1 = xcur4 + (size_t)r1 * CH + c;
        const float4* p2 = xcur4 + (size_t)r2 * CH + c;
        const float4* p3 = xcur4 + (size_t)r3 * CH + c;
        float4 v00 = p0[0], v01 = p0[1];
        float4 v10 = p1[0], v11 = p1[1];
        float4 v20 = p2[0], v21 = p2[1];
        float4 v30 = p3[0], v31 = p3[1];
        ax0.x += a0.y * v00.x + a1.y * v10.x + a2.y * v20.x + a3.y * v30.x;
        ax0.y += a0.y * v00.y + a1.y * v10.y + a2.y * v20.y + a3.y * v30.y;
        ax0.z += a0.y * v00.z + a1.y * v10.z + a2.y * v20.z + a3.y * v30.z;
        ax0.w += a0.y * v00.w + a1.y * v10.w + a2.y * v20.w + a3.y * v30.w;
        ax1.x += a0.y * v01.x + a1.y * v11.x + a2.y * v21.x + a3.y * v31.x;
        ax1.y += a0.y * v01.y + a1.y * v11.y + a2.y * v21.y + a3.y * v31.y;
        ax1.z += a0.y * v01.z + a1.y * v11.z + a2.y * v21.z + a3.y * v31.z;
        ax1.w += a0.y * v01.w + a1.y * v11.w + a2.y * v21.w + a3.y * v31.w;
    }
    for (; j < e_end; ++j) {
        float2 a = edat[j];
        int r = __float_as_int(a.x);
        const float4* p = xcur4 + (size_t)r * CH + c;
        float4 v0 = p[0], v1 = p[1];
        ax0.x += a.y * v0.x; ax0.y += a.y * v0.y; ax0.z += a.y * v0.z; ax0.w += a.y * v0.w;
        ax1.x += a.y * v1.x; ax1.y += a.y * v1.y; ax1.z += a.y * v1.z; ax1.w += a.y * v1.w;
    }
    float h = hopwise[hop];
    size_t o = (size_t)node * CH + c;
    float4 b0 = bvec4[o], b1 = bvec4[o + 1];
    float4 xv0, xv1;
    xv0.x = ax0.x + b0.x; xv0.y = ax0.y + b0.y; xv0.z = ax0.z + b0.z; xv0.w = ax0.w + b0.w;
    xv1.x = ax1.x + b1.x; xv1.y = ax1.y + b1.y; xv1.z = ax1.z + b1.z; xv1.w = ax1.w + b1.w;
    if (writeNext) { xnext4[o] = xv0; xnext4[o + 1] = xv1; }
    float4 ov0 = out4[o], ov1 = out4[o + 1];
    ov0.x += h * xv0.x; ov0.y += h * xv0.y; ov0.z += h * xv0.z; ov0.w += h * xv0.w;
    ov1.x += h * xv1.x; ov1.y += h * xv1.y; ov1.z += h * xv1.z; ov1.w += h * xv1.w;
    out4[o] = ov0; out4[o + 1] = ov1;
}

extern "C" void kernel_launch(void* const* d_in, const int* in_sizes, int n_in,
                              void* d_out, int out_size, void* d_ws, size_t ws_size,
                              hipStream_t stream) {
    const float* x       = (const float*)d_in[0];
    const float* ef      = (const float*)d_in[1];
    const float* hopwise = (const float*)d_in[2];
    const int*   eidx    = (const int*)d_in[3];

    const int E = in_sizes[3] / 2;
    const int D = in_sizes[1] / E;          // 96
    const int N = in_sizes[0] / D;          // 50000
    const int K = in_sizes[2] - 1;          // 3
    const int NC2 = N * CH2;                // node-pairchunks

    const int* row = eidx;
    const int* col = eidx + E;
    float* out = (float*)d_out;

    // Workspace layout (N even, E multiple of 4 -> 16B alignment holds)
    char* w = (char*)d_ws;
    int*    deg    = (int*)w;     w += (size_t)N * 4;
    int*    starts = (int*)w;     w += (size_t)(N + 8) * 4;
    int*    cursor = (int*)w;     w += (size_t)N * 4;
    float*  deginv = (float*)w;   w += (size_t)N * 4;
    int*    bsums  = (int*)w;     w += 256 * 4;
    float2* edat   = (float2*)w;  w += (size_t)E * 8;
    float*  bvec   = (float*)w;   w += (size_t)N * D * 4;
    float*  buf0   = (float*)w;   w += (size_t)N * D * 4;
    float*  buf1   = (float*)w;   /* w += N*D*4 */

    const int BT = 256;
    const int nScanBlocks = (N + 1023) / 1024;

    // CSR build + b scatter
    hipMemsetAsync(deg, 0, (size_t)N * sizeof(int), stream);
    hipMemsetAsync(bvec, 0, (size_t)N * D * sizeof(float), stream);
    deg_kernel<<<(E + BT - 1) / BT, BT, 0, stream>>>(col, deg, E);
    deginv_kernel<<<(N + BT - 1) / BT, BT, 0, stream>>>(deg, deginv, N);
    {
        long long tot = (long long)E * CH2;
        int blocks = (int)((tot + 255) / 256);
        scatter_b_kernel<<<blocks, 256, 0, stream>>>(row, col, deginv, (const float4*)ef,
                                                     bvec, E);
    }
    scan1_kernel<<<nScanBlocks, 256, 0, stream>>>(deg, starts, bsums, N);
    scan2_kernel<<<1, 64, 0, stream>>>(bsums, nScanBlocks, starts, N, E);
    scan3_kernel<<<nScanBlocks, 256, 0, stream>>>(starts, cursor, bsums, N);
    fill_kernel<<<(E + BT - 1) / BT, BT, 0, stream>>>(col, row, deginv, cursor, edat, E);

    // hop 1 (x-gather + b + out init)
    int hopBlocks = (NC2 + 255) / 256;
    hop1_kernel<<<hopBlocks, 256, 0, stream>>>(starts, edat, (const float4*)x,
                                               (const float4*)bvec, (float4*)buf0,
                                               (float4*)out, hopwise, NC2);

    // hops 2..K
    const float* xcur = buf0;
    for (int hop = 2; hop <= K; ++hop) {
        float* xnext = (hop & 1) ? buf1 : buf0;
        if (xnext == xcur) xnext = (xcur == buf0) ? buf1 : buf0;
        int writeNext = (hop < K) ? 1 : 0;
        hop_kernel<<<hopBlocks, 256, 0, stream>>>(starts, edat, (const float4*)xcur,
                                                  (const float4*)bvec, (float4*)xnext,
                                                  (float4*)out, hopwise, hop, writeNext, NC2);
        xcur = xnext;
    }
}

// Round 6
// 661.946 us; speedup vs baseline: 4.6232x; 4.6232x over previous
//
#include <hip/hip_runtime.h>

// STGNN K-hop propagation, CSR-by-destination.
//   norm[e] = deginv[row[e]]*deginv[col[e]]
//   b[n,:]  = sum_in norm*ef      (hop-invariant, computed inside fused hop1)
//   hop1 (fused): x1 = S*x + b; out = h0*x + h1*x1; bvec = b
//   hops 2..K:    xk = S*x_{k-1} + b; out += hk*xk
// Thread mapping: g -> node = g/12, c = g%12; thread owns chunks {c, c+12}
// (SPLIT-HALF, not {2c,2c+1}): per gather instruction the 12 lanes read
// CONSECUTIVE 16B -> 4 lanes/64B line -> half the TA line-transactions of the
// stride-32B pairing. R5 scatter experiment reverted (atomics: 8x regression).

#define CH 24   // float4 chunks per 96-float row
#define CH2 12  // threads per node; thread c owns float4 chunks c and c+12

// Clang ext-vector for __builtin_nontemporal_load (HIP float4 is a class type,
// which the builtin rejects).
typedef float v4f __attribute__((ext_vector_type(4)));

__global__ void deg_kernel(const int* __restrict__ col, int* __restrict__ deg, int E) {
    int e = blockIdx.x * blockDim.x + threadIdx.x;
    if (e < E) atomicAdd(&deg[col[e]], 1);
}

__global__ void deginv_kernel(const int* __restrict__ deg, float* __restrict__ deginv, int n) {
    int i = blockIdx.x * blockDim.x + threadIdx.x;
    if (i < n) {
        int d = deg[i];
        deginv[i] = (d > 0) ? rsqrtf((float)d) : 0.0f;
    }
}

// ---- hierarchical exclusive scan: 1024 elems/block ----
__global__ __launch_bounds__(256) void scan1_kernel(const int* __restrict__ deg,
                                                    int* __restrict__ starts,
                                                    int* __restrict__ bsums, int n) {
    int t = threadIdx.x;
    int i = blockIdx.x * 1024 + t * 4;
    int4 v = make_int4(0, 0, 0, 0);
    if (i + 3 < n) v = *(const int4*)(deg + i);
    else {
        if (i + 0 < n) v.x = deg[i + 0];
        if (i + 1 < n) v.y = deg[i + 1];
        if (i + 2 < n) v.z = deg[i + 2];
        if (i + 3 < n) v.w = deg[i + 3];
    }
    int s0 = v.x, s1 = s0 + v.y, s2 = s1 + v.z, s3 = s2 + v.w;
    int tot = s3;
    int lane = t & 63;
    int incl = tot;
    for (int off = 1; off < 64; off <<= 1) {
        int u = __shfl_up(incl, off, 64);
        if (lane >= off) incl += u;
    }
    __shared__ int wsum[4];
    __shared__ int woff[4];
    int wid = t >> 6;
    if (lane == 63) wsum[wid] = incl;
    __syncthreads();
    if (t == 0) { int a = 0; for (int w = 0; w < 4; ++w) { woff[w] = a; a += wsum[w]; } }
    __syncthreads();
    int excl = incl - tot + woff[wid];
    if (i + 0 < n) starts[i + 0] = excl;
    if (i + 1 < n) starts[i + 1] = excl + s0;
    if (i + 2 < n) starts[i + 2] = excl + s1;
    if (i + 3 < n) starts[i + 3] = excl + s2;
    if (t == 255) bsums[blockIdx.x] = woff[3] + wsum[3];
}

__global__ __launch_bounds__(64) void scan2_kernel(int* __restrict__ bsums, int nb,
                                                   int* __restrict__ starts, int n, int total) {
    int lane = threadIdx.x;
    int v = (lane < nb) ? bsums[lane] : 0;
    int incl = v;
    for (int off = 1; off < 64; off <<= 1) {
        int u = __shfl_up(incl, off, 64);
        if (lane >= off) incl += u;
    }
    if (lane < nb) bsums[lane] = incl - v;
    if (lane == 0) starts[n] = total;
}

__global__ __launch_bounds__(256) void scan3_kernel(int* __restrict__ starts,
                                                    int* __restrict__ cursor,
                                                    const int* __restrict__ bsums, int n) {
    int t = threadIdx.x;
    int i = blockIdx.x * 1024 + t * 4;
    int off = bsums[blockIdx.x];
    for (int k = 0; k < 4; ++k) {
        int ii = i + k;
        if (ii < n) {
            int s = starts[ii] + off;
            starts[ii] = s;
            cursor[ii] = s;
        }
    }
}

// Fused fill+slot: place edge in CSR slot AND write (row, norm) metadata in one pass.
__global__ void fill_kernel(const int* __restrict__ col, const int* __restrict__ row,
                            const float* __restrict__ deginv, int* __restrict__ cursor,
                            int* __restrict__ eids, float2* __restrict__ edat, int E) {
    int e = blockIdx.x * blockDim.x + threadIdx.x;
    if (e < E) {
        int c = col[e], r = row[e];
        int pos = atomicAdd(&cursor[c], 1);
        eids[pos] = e;
        float2 o;
        o.x = __int_as_float(r);
        o.y = deginv[r] * deginv[c];
        edat[pos] = o;
    }
}

// Fused hop1: b = sum norm*ef; x1 = sum norm*x[row] + b; out = h0*x + h1*x1.
// ef loads are nontemporal (single-use 307MB stream must not thrash L3).
__global__ __launch_bounds__(256) void hop1_kernel(const int* __restrict__ starts,
                                                   const float2* __restrict__ edat,
                                                   const int* __restrict__ eids,
                                                   const float4* __restrict__ ef4,
                                                   const float4* __restrict__ x4,
                                                   float4* __restrict__ bvec4,
                                                   float4* __restrict__ xnext4,
                                                   float4* __restrict__ out4,
                                                   const float* __restrict__ hopwise,
                                                   int NC2) {
    int g = blockIdx.x * 256 + threadIdx.x;
    if (g >= NC2) return;
    int node = g / CH2;
    int c = g - node * CH2;          // this thread owns chunks c and c+12
    int s = starts[node], e_end = starts[node + 1];
    float4 ab0 = make_float4(0.f, 0.f, 0.f, 0.f), ab1 = ab0;
    float4 ax0 = ab0, ax1 = ab0;
    int j = s;
    for (; j + 2 <= e_end; j += 2) {
        float2 a0 = edat[j], a1 = edat[j + 1];
        int e0 = eids[j], e1 = eids[j + 1];
        int r0 = __float_as_int(a0.x), r1 = __float_as_int(a1.x);
        const v4f* fp0 = (const v4f*)(ef4 + (size_t)e0 * CH + c);
        const v4f* fp1 = (const v4f*)(ef4 + (size_t)e1 * CH + c);
        const float4* xp0 = x4 + (size_t)r0 * CH + c;
        const float4* xp1 = x4 + (size_t)r1 * CH + c;
        v4f f00 = __builtin_nontemporal_load(fp0);
        v4f f01 = __builtin_nontemporal_load(fp0 + 12);
        v4f f10 = __builtin_nontemporal_load(fp1);
        v4f f11 = __builtin_nontemporal_load(fp1 + 12);
        float4 v00 = xp0[0], v01 = xp0[12];
        float4 v10 = xp1[0], v11 = xp1[12];
        ab0.x += a0.y * f00.x + a1.y * f10.x;
        ab0.y += a0.y * f00.y + a1.y * f10.y;
        ab0.z += a0.y * f00.z + a1.y * f10.z;
        ab0.w += a0.y * f00.w + a1.y * f10.w;
        ab1.x += a0.y * f01.x + a1.y * f11.x;
        ab1.y += a0.y * f01.y + a1.y * f11.y;
        ab1.z += a0.y * f01.z + a1.y * f11.z;
        ab1.w += a0.y * f01.w + a1.y * f11.w;
        ax0.x += a0.y * v00.x + a1.y * v10.x;
        ax0.y += a0.y * v00.y + a1.y * v10.y;
        ax0.z += a0.y * v00.z + a1.y * v10.z;
        ax0.w += a0.y * v00.w + a1.y * v10.w;
        ax1.x += a0.y * v01.x + a1.y * v11.x;
        ax1.y += a0.y * v01.y + a1.y * v11.y;
        ax1.z += a0.y * v01.z + a1.y * v11.z;
        ax1.w += a0.y * v01.w + a1.y * v11.w;
    }
    for (; j < e_end; ++j) {
        float2 a = edat[j];
        int e = eids[j];
        int r = __float_as_int(a.x);
        const v4f* fp = (const v4f*)(ef4 + (size_t)e * CH + c);
        const float4* xp = x4 + (size_t)r * CH + c;
        v4f f0 = __builtin_nontemporal_load(fp);
        v4f f1 = __builtin_nontemporal_load(fp + 12);
        float4 v0 = xp[0], v1 = xp[12];
        ab0.x += a.y * f0.x; ab0.y += a.y * f0.y; ab0.z += a.y * f0.z; ab0.w += a.y * f0.w;
        ab1.x += a.y * f1.x; ab1.y += a.y * f1.y; ab1.z += a.y * f1.z; ab1.w += a.y * f1.w;
        ax0.x += a.y * v0.x; ax0.y += a.y * v0.y; ax0.z += a.y * v0.z; ax0.w += a.y * v0.w;
        ax1.x += a.y * v1.x; ax1.y += a.y * v1.y; ax1.z += a.y * v1.z; ax1.w += a.y * v1.w;
    }
    float h0 = hopwise[0], h1 = hopwise[1];
    size_t o = (size_t)node * CH + c;
    float4 xs0 = x4[o], xs1 = x4[o + 12];
    float4 x10, x11;
    x10.x = ax0.x + ab0.x; x10.y = ax0.y + ab0.y; x10.z = ax0.z + ab0.z; x10.w = ax0.w + ab0.w;
    x11.x = ax1.x + ab1.x; x11.y = ax1.y + ab1.y; x11.z = ax1.z + ab1.z; x11.w = ax1.w + ab1.w;
    bvec4[o] = ab0; bvec4[o + 12] = ab1;
    xnext4[o] = x10; xnext4[o + 12] = x11;
    float4 ov0, ov1;
    ov0.x = h0 * xs0.x + h1 * x10.x; ov0.y = h0 * xs0.y + h1 * x10.y;
    ov0.z = h0 * xs0.z + h1 * x10.z; ov0.w = h0 * xs0.w + h1 * x10.w;
    ov1.x = h0 * xs1.x + h1 * x11.x; ov1.y = h0 * xs1.y + h1 * x11.y;
    ov1.z = h0 * xs1.z + h1 * x11.z; ov1.w = h0 * xs1.w + h1 * x11.w;
    out4[o] = ov0; out4[o + 12] = ov1;
}

// hops 2..K: xk = S*x_{k-1} + b; out += hk*xk.  writeNext=0 on the last hop
// (xnext is dead there; saves a 19.2MB store stream).
__global__ __launch_bounds__(256) void hop_kernel(const int* __restrict__ starts,
                                                  const float2* __restrict__ edat,
                                                  const float4* __restrict__ xcur4,
                                                  const float4* __restrict__ bvec4,
                                                  float4* __restrict__ xnext4,
                                                  float4* __restrict__ out4,
                                                  const float* __restrict__ hopwise,
                                                  int hop, int writeNext, int NC2) {
    int g = blockIdx.x * 256 + threadIdx.x;
    if (g >= NC2) return;
    int node = g / CH2;
    int c = g - node * CH2;          // this thread owns chunks c and c+12
    int s = starts[node], e_end = starts[node + 1];
    float4 ax0 = make_float4(0.f, 0.f, 0.f, 0.f), ax1 = ax0;
    int j = s;
    for (; j + 4 <= e_end; j += 4) {
        float2 a0 = edat[j], a1 = edat[j + 1], a2 = edat[j + 2], a3 = edat[j + 3];
        int r0 = __float_as_int(a0.x), r1 = __float_as_int(a1.x);
        int r2 = __float_as_int(a2.x), r3 = __float_as_int(a3.x);
        const float4* p0 = xcur4 + (size_t)r0 * CH + c;
        const float4* p1 = xcur4 + (size_t)r1 * CH + c;
        const float4* p2 = xcur4 + (size_t)r2 * CH + c;
        const float4* p3 = xcur4 + (size_t)r3 * CH + c;
        float4 v00 = p0[0], v01 = p0[12];
        float4 v10 = p1[0], v11 = p1[12];
        float4 v20 = p2[0], v21 = p2[12];
        float4 v30 = p3[0], v31 = p3[12];
        ax0.x += a0.y * v00.x + a1.y * v10.x + a2.y * v20.x + a3.y * v30.x;
        ax0.y += a0.y * v00.y + a1.y * v10.y + a2.y * v20.y + a3.y * v30.y;
        ax0.z += a0.y * v00.z + a1.y * v10.z + a2.y * v20.z + a3.y * v30.z;
        ax0.w += a0.y * v00.w + a1.y * v10.w + a2.y * v20.w + a3.y * v30.w;
        ax1.x += a0.y * v01.x + a1.y * v11.x + a2.y * v21.x + a3.y * v31.x;
        ax1.y += a0.y * v01.y + a1.y * v11.y + a2.y * v21.y + a3.y * v31.y;
        ax1.z += a0.y * v01.z + a1.y * v11.z + a2.y * v21.z + a3.y * v31.z;
        ax1.w += a0.y * v01.w + a1.y * v11.w + a2.y * v21.w + a3.y * v31.w;
    }
    for (; j < e_end; ++j) {
        float2 a = edat[j];
        int r = __float_as_int(a.x);
        const float4* p = xcur4 + (size_t)r * CH + c;
        float4 v0 = p[0], v1 = p[12];
        ax0.x += a.y * v0.x; ax0.y += a.y * v0.y; ax0.z += a.y * v0.z; ax0.w += a.y * v0.w;
        ax1.x += a.y * v1.x; ax1.y += a.y * v1.y; ax1.z += a.y * v1.z; ax1.w += a.y * v1.w;
    }
    float h = hopwise[hop];
    size_t o = (size_t)node * CH + c;
    float4 b0 = bvec4[o], b1 = bvec4[o + 12];
    float4 xv0, xv1;
    xv0.x = ax0.x + b0.x; xv0.y = ax0.y + b0.y; xv0.z = ax0.z + b0.z; xv0.w = ax0.w + b0.w;
    xv1.x = ax1.x + b1.x; xv1.y = ax1.y + b1.y; xv1.z = ax1.z + b1.z; xv1.w = ax1.w + b1.w;
    if (writeNext) { xnext4[o] = xv0; xnext4[o + 12] = xv1; }
    float4 ov0 = out4[o], ov1 = out4[o + 12];
    ov0.x += h * xv0.x; ov0.y += h * xv0.y; ov0.z += h * xv0.z; ov0.w += h * xv0.w;
    ov1.x += h * xv1.x; ov1.y += h * xv1.y; ov1.z += h * xv1.z; ov1.w += h * xv1.w;
    out4[o] = ov0; out4[o + 12] = ov1;
}

extern "C" void kernel_launch(void* const* d_in, const int* in_sizes, int n_in,
                              void* d_out, int out_size, void* d_ws, size_t ws_size,
                              hipStream_t stream) {
    const float* x       = (const float*)d_in[0];
    const float* ef      = (const float*)d_in[1];
    const float* hopwise = (const float*)d_in[2];
    const int*   eidx    = (const int*)d_in[3];

    const int E = in_sizes[3] / 2;
    const int D = in_sizes[1] / E;          // 96
    const int N = in_sizes[0] / D;          // 50000
    const int K = in_sizes[2] - 1;          // 3
    const int NC2 = N * CH2;                // node-chunks (12 per node)

    const int* row = eidx;
    const int* col = eidx + E;
    float* out = (float*)d_out;

    // Workspace layout (N even, E multiple of 4 -> 16B alignment holds)
    char* w = (char*)d_ws;
    int*    deg    = (int*)w;     w += (size_t)N * 4;
    int*    starts = (int*)w;     w += (size_t)(N + 8) * 4;
    int*    cursor = (int*)w;     w += (size_t)N * 4;
    int*    eids   = (int*)w;     w += (size_t)E * 4;
    float*  deginv = (float*)w;   w += (size_t)N * 4;
    int*    bsums  = (int*)w;     w += 256 * 4;
    float2* edat   = (float2*)w;  w += (size_t)E * 8;
    float*  bvec   = (float*)w;   w += (size_t)N * D * 4;
    float*  buf0   = (float*)w;   w += (size_t)N * D * 4;
    float*  buf1   = (float*)w;   /* w += N*D*4 */

    const int BT = 256;
    const int nScanBlocks = (N + 1023) / 1024;

    // CSR build
    hipMemsetAsync(deg, 0, (size_t)N * sizeof(int), stream);
    deg_kernel<<<(E + BT - 1) / BT, BT, 0, stream>>>(col, deg, E);
    deginv_kernel<<<(N + BT - 1) / BT, BT, 0, stream>>>(deg, deginv, N);
    scan1_kernel<<<nScanBlocks, 256, 0, stream>>>(deg, starts, bsums, N);
    scan2_kernel<<<1, 64, 0, stream>>>(bsums, nScanBlocks, starts, N, E);
    scan3_kernel<<<nScanBlocks, 256, 0, stream>>>(starts, cursor, bsums, N);
    fill_kernel<<<(E + BT - 1) / BT, BT, 0, stream>>>(col, row, deginv, cursor, eids, edat, E);

    // Fused hop 1 (+ b computation + out init)
    int hopBlocks = (NC2 + 255) / 256;
    hop1_kernel<<<hopBlocks, 256, 0, stream>>>(starts, edat, eids, (const float4*)ef,
                                               (const float4*)x, (float4*)bvec,
                                               (float4*)buf0, (float4*)out, hopwise, NC2);

    // hops 2..K
    const float* xcur = buf0;
    for (int hop = 2; hop <= K; ++hop) {
        float* xnext = (hop & 1) ? buf1 : buf0;
        if (xnext == xcur) xnext = (xcur == buf0) ? buf1 : buf0;
        int writeNext = (hop < K) ? 1 : 0;
        hop_kernel<<<hopBlocks, 256, 0, stream>>>(starts, edat, (const float4*)xcur,
                                                  (const float4*)bvec, (float4*)xnext,
                                                  (float4*)out, hopwise, hop, writeNext, NC2);
        xcur = xnext;
    }
}